// Round 8
// baseline (320.691 us; speedup 1.0000x reference)
//
#include <hip/hip_runtime.h>
#include <math.h>

#define B_  2
#define C_  256
#define NH_ 8
#define HD_ 32
#define L_  4096           // 64*64 (both Lq and Lkv)
#define M_  (B_*L_)        // 8192

typedef __attribute__((ext_vector_type(8))) short bf16x8;
typedef __attribute__((ext_vector_type(4))) float f32x4;

// fp32 -> bf16 round-to-nearest-even (bit trick; values are tame, no NaN)
__device__ __forceinline__ unsigned short f2bf(float x) {
    unsigned u = __float_as_uint(x);
    unsigned r = u + 0x7fffu + ((u >> 16) & 1u);
    return (unsigned short)(r >> 16);
}

#define GLOAD_LDS16(gp, lp) \
    __builtin_amdgcn_global_load_lds( \
        (const __attribute__((address_space(1))) void*)(gp), \
        (__attribute__((address_space(3))) void*)(lp), 16, 0, 0)

// ---------------------------------------------------------------------------
// kv[b][l][j] for j<256: j = c*9 + kh*3 + kw ; h=2*oh+kh-1, w=2*ow+kw-1
// ---------------------------------------------------------------------------
__global__ __launch_bounds__(256) void build_kv_kernel(
    const float* __restrict__ feat, float* __restrict__ kv)
{
    int idx = blockIdx.x * 256 + threadIdx.x;   // B*L*C = 4M threads
    int j = idx & (C_ - 1);
    int l = (idx >> 8) & (L_ - 1);
    int b = idx >> 20;
    int c  = j / 9;
    int r  = j - c * 9;
    int kh = r / 3;
    int kw = r - kh * 3;
    int oh = l >> 6, ow = l & 63;
    int h = 2 * oh + kh - 1;
    int w = 2 * ow + kw - 1;
    float val = 0.0f;
    if ((unsigned)h < 128u && (unsigned)w < 128u)
        val = feat[((size_t)(b * C_ + c) * 128 + h) * 128 + w];
    kv[idx] = val;
}

// ---------------------------------------------------------------------------
// out[m][n] = (sum_c A[m][c] * W[n][c] + bias[n]) * oscale(OMODE1)
// TRANS_A: A element (m,c) at A[b*C*L + c*L + l]  (m = b*L + l)
// OMODE: 1 = bf16 row-major [m][256], scaled by oscale (Q: folds 1/sqrt(d)*log2e)
//        2 = bf16 transposed [b*256+n][key]   (V^T for attention)
//        3 = fp32 fused gate: out[b*C*L+n*L+l] = (val+bias)*src[same]
// ---------------------------------------------------------------------------
template <bool TRANS_A, int OMODE>
__global__ __launch_bounds__(256) void gemm_kernel(
    const float* __restrict__ A, const float* __restrict__ W,
    const float* __restrict__ bias, void* __restrict__ out,
    const float* __restrict__ src, float oscale)
{
    __shared__ float As[32][68];
    __shared__ float Ws[32][68];

    const int m0 = blockIdx.x * 64;
    const int n0 = blockIdx.y * 64;
    const int t  = threadIdx.x;
    const int tm = t >> 4;        // 0..15
    const int tn = t & 15;        // 0..15

    float acc[4][4] = {};

    for (int k0 = 0; k0 < C_; k0 += 32) {
        if (!TRANS_A) {
            #pragma unroll
            for (int u = t; u < 512; u += 256) {
                int row = u >> 3, c4 = u & 7;
                float4 val = *(const float4*)(A + (size_t)(m0 + row) * C_ + k0 + c4 * 4);
                As[c4 * 4 + 0][row] = val.x;
                As[c4 * 4 + 1][row] = val.y;
                As[c4 * 4 + 2][row] = val.z;
                As[c4 * 4 + 3][row] = val.w;
            }
        } else {
            int b  = m0 >> 12;          // tile never straddles batch (L%64==0)
            int l0 = m0 & (L_ - 1);
            #pragma unroll
            for (int u = t; u < 512; u += 256) {
                int c = u >> 4, l4 = u & 15;
                float4 val = *(const float4*)(A + (size_t)b * C_ * L_ +
                                              (size_t)(k0 + c) * L_ + l0 + l4 * 4);
                *(float4*)&As[c][l4 * 4] = val;
            }
        }
        #pragma unroll
        for (int u = t; u < 512; u += 256) {
            int row = u >> 3, c4 = u & 7;
            float4 val = *(const float4*)(W + (size_t)(n0 + row) * C_ + k0 + c4 * 4);
            Ws[c4 * 4 + 0][row] = val.x;
            Ws[c4 * 4 + 1][row] = val.y;
            Ws[c4 * 4 + 2][row] = val.z;
            Ws[c4 * 4 + 3][row] = val.w;
        }
        __syncthreads();
        #pragma unroll
        for (int kk = 0; kk < 32; kk++) {
            float4 a4 = *(float4*)&As[kk][tm * 4];
            float4 w4 = *(float4*)&Ws[kk][tn * 4];
            float a[4] = {a4.x, a4.y, a4.z, a4.w};
            float w[4] = {w4.x, w4.y, w4.z, w4.w};
            #pragma unroll
            for (int i = 0; i < 4; i++)
                #pragma unroll
                for (int jj = 0; jj < 4; jj++)
                    acc[i][jj] += a[i] * w[jj];
        }
        __syncthreads();
    }

    if (OMODE == 1) {
        unsigned short* o = (unsigned short*)out;
        #pragma unroll
        for (int i = 0; i < 4; i++) {
            int m = m0 + tm * 4 + i;
            int n = n0 + tn * 4;
            ushort4 pk = make_ushort4(
                f2bf((acc[i][0] + bias[n + 0]) * oscale),
                f2bf((acc[i][1] + bias[n + 1]) * oscale),
                f2bf((acc[i][2] + bias[n + 2]) * oscale),
                f2bf((acc[i][3] + bias[n + 3]) * oscale));
            *(ushort4*)(o + ((size_t)m << 8) + n) = pk;
        }
    } else if (OMODE == 2) {
        unsigned short* o = (unsigned short*)out;
        int b = m0 >> 12;
        int key = (m0 & (L_ - 1)) + tm * 4;
        #pragma unroll
        for (int jj = 0; jj < 4; jj++) {
            int n = n0 + tn * 4 + jj;
            float bb = bias[n];
            ushort4 pk = make_ushort4(
                f2bf(acc[0][jj] + bb), f2bf(acc[1][jj] + bb),
                f2bf(acc[2][jj] + bb), f2bf(acc[3][jj] + bb));
            *(ushort4*)(o + ((size_t)(b * 256 + n) << 12) + key) = pk;
        }
    } else {   // OMODE == 3: fp32, fused * src, [b][n][l] layout
        float* o = (float*)out;
        #pragma unroll
        for (int i = 0; i < 4; i++) {
            int m = m0 + tm * 4 + i;
            int b = m >> 12, l = m & (L_ - 1);
            #pragma unroll
            for (int jj = 0; jj < 4; jj++) {
                int n = n0 + tn * 4 + jj;
                float val = acc[i][jj] + bias[n];
                size_t oidx = (size_t)(b * C_ + n) * L_ + l;
                o[oidx] = val * src[oidx];
            }
        }
    }
}

// ---------------------------------------------------------------------------
// MFMA flash attention, K-split x2 (bf16 inputs, fp32 accum).
// 512 thr = 8 waves. Wave (wl, halfid): q-rows qt*64+wl*16..+16, keys
// halfid*2048..+2048 (32 tiles). Each half stages its own K/V tile.
// Swapped QK: S^T[key][q] = mfma(A=K, B=Q^T); per-lane online softmax in the
// log2 domain (scale*log2e folded into Q projection -> exp2f = bare v_exp).
// P^T built in-register via shfl; O^T accumulated via mfma(A=V^T, B=P^T).
// Final: the two halves' (m,l,O) merged through LDS; half 0 writes output.
// ---------------------------------------------------------------------------
__global__ __launch_bounds__(512) void attn_mfma_kernel(
    const unsigned short* __restrict__ qbf,   // [M][256] bf16 (Q pre-scaled)
    const unsigned short* __restrict__ kbf,   // [M][256] bf16 row-major
    const unsigned short* __restrict__ vbf,   // [B*256][4096] bf16 (V^T)
    float* __restrict__ ob)                   // [M][256] fp32 row-major
{
    __shared__ __align__(16) char Ksh[2][4096];
    __shared__ __align__(16) char Vsh[2][4096];
    __shared__ float mb[4][64][11];   // half-1 state: 8 O + m + l (pad 11)

    const int id   = blockIdx.x;
    const int xcd  = id & 7;
    const int slot = id >> 3;
    const int bh   = xcd + 8 * (slot >> 6);
    const int qt   = slot & 63;
    const int b = bh >> 3, h = bh & 7;

    const int t      = threadIdx.x;
    const int lane   = t & 63;
    const int wl     = (t >> 6) & 3;  // wave within half
    const int halfid = t >> 8;        // 0/1: K-range half
    const int th     = t & 255;       // thread within half
    const int lg     = lane >> 4;     // 0..3
    const int lc     = lane & 15;     // 0..15

    // Q^T B-fragment (Q pre-scaled by 1/sqrt(32)*log2e at projection)
    const int qrow = qt * 64 + wl * 16 + lc;
    const bf16x8 qf = *(const bf16x8*)(qbf + ((size_t)(b * L_ + qrow) << 8) + h * 32 + (lg << 3));

    // staging sources for this half's K-range
    const char* kg = (const char*)kbf
        + ((size_t)(b * L_ + halfid * 2048 + wl * 16 + lc) << 9) + h * 64 + (lg << 4);
    const int vmt = (t >> 7) & 1, vks = wl & 1;
    const char* vg = (const char*)vbf
        + ((size_t)(b * 256 + h * 32 + vmt * 16 + lc) << 13)
        + ((size_t)(halfid * 2048 + vks * 32 + (lg << 3)) << 1);
    char* kdst = Ksh[halfid] + th * 16;
    char* vdst = Vsh[halfid] + th * 16;
    const char* kbase = Ksh[halfid];
    const char* vbase = Vsh[halfid];

    f32x4 oacc[2];
    oacc[0] = (f32x4){0.f, 0.f, 0.f, 0.f};
    oacc[1] = (f32x4){0.f, 0.f, 0.f, 0.f};
    float mrun = -INFINITY, lrun = 0.0f;
    const f32x4 zero4 = (f32x4){0.f, 0.f, 0.f, 0.f};

    for (int kt = 0; kt < 32; kt++) {
        __syncthreads();   // all waves done reading previous tile
        GLOAD_LDS16(kg + (size_t)kt * 32768, kdst);
        GLOAD_LDS16(vg + (size_t)kt * 128,   vdst);
        __syncthreads();   // vmcnt drained -> tiles ready

        // ---- S^T = K x Q^T : 4 key-group fragments (log2-scaled scores) ----
        f32x4 sa[4];
        #pragma unroll
        for (int f = 0; f < 4; f++) {
            bf16x8 kf = *(const bf16x8*)(kbase + f * 1024 + lane * 16);
            sa[f] = __builtin_amdgcn_mfma_f32_16x16x32_bf16(kf, qf, zero4, 0, 0, 0);
        }

        // ---- online softmax (log2 domain) for column q=lc ----
        float sv[16];
        #pragma unroll
        for (int f = 0; f < 4; f++)
            #pragma unroll
            for (int i = 0; i < 4; i++)
                sv[f * 4 + i] = sa[f][i];
        float t0 = fmaxf(fmaxf(sv[0], sv[1]),  fmaxf(sv[2], sv[3]));
        float t1 = fmaxf(fmaxf(sv[4], sv[5]),  fmaxf(sv[6], sv[7]));
        float t2 = fmaxf(fmaxf(sv[8], sv[9]),  fmaxf(sv[10], sv[11]));
        float t3 = fmaxf(fmaxf(sv[12], sv[13]), fmaxf(sv[14], sv[15]));
        float tmax = fmaxf(fmaxf(t0, t1), fmaxf(t2, t3));
        tmax = fmaxf(tmax, __shfl_xor(tmax, 16));
        tmax = fmaxf(tmax, __shfl_xor(tmax, 32));
        float mnew   = fmaxf(mrun, tmax);
        float factor = exp2f(mrun - mnew);
        float pv[16];
        float ps = 0.f;
        #pragma unroll
        for (int j2 = 0; j2 < 16; j2++) {
            float p = exp2f(sv[j2] - mnew);
            pv[j2] = p;
            ps += p;
        }
        ps += __shfl_xor(ps, 16);
        ps += __shfl_xor(ps, 32);
        lrun = lrun * factor + ps;
        mrun = mnew;
        #pragma unroll
        for (int i = 0; i < 4; i++) { oacc[0][i] *= factor; oacc[1][i] *= factor; }

        // ---- pack P to bf16 pairs: W8[f*2+m] = keys f*16+lg*4+{2m,2m+1} ----
        unsigned W8[8];
        #pragma unroll
        for (int f = 0; f < 4; f++)
            #pragma unroll
            for (int m2 = 0; m2 < 2; m2++)
                W8[f * 2 + m2] = (unsigned)f2bf(pv[f * 4 + 2 * m2])
                               | ((unsigned)f2bf(pv[f * 4 + 2 * m2 + 1]) << 16);

        // ---- build P^T B-fragments in-register and do PV ----
        #pragma unroll
        for (int ks = 0; ks < 2; ks++) {
            union { unsigned u[4]; bf16x8 v; } bu;
            #pragma unroll
            for (int j = 0; j < 4; j++) {
                // word j needs keys ks*32 + lg*8 + 2j,2j+1 of column lc:
                // holder lane (g_h, lc), frag f = ks*2 + (lg>>1), word m = j&1
                int srcl = lc + 16 * ((lg & 1) * 2 + (j >> 1));
                unsigned va = (unsigned)__shfl((int)W8[(ks * 2) * 2 + (j & 1)], srcl);
                unsigned vb = (unsigned)__shfl((int)W8[(ks * 2 + 1) * 2 + (j & 1)], srcl);
                bu.u[j] = (lg >= 2) ? vb : va;
            }
            bf16x8 v0 = *(const bf16x8*)(vbase + 0 * 2048 + ks * 1024 + lane * 16);
            bf16x8 v1 = *(const bf16x8*)(vbase + 1 * 2048 + ks * 1024 + lane * 16);
            oacc[0] = __builtin_amdgcn_mfma_f32_16x16x32_bf16(v0, bu.v, oacc[0], 0, 0, 0);
            oacc[1] = __builtin_amdgcn_mfma_f32_16x16x32_bf16(v1, bu.v, oacc[1], 0, 0, 0);
        }
    }

    // ---- merge the two K-halves' online states, half 0 writes output ----
    __syncthreads();
    if (halfid == 1) {
        float* s = &mb[wl][lane][0];
        #pragma unroll
        for (int i = 0; i < 4; i++) { s[i] = oacc[0][i]; s[4 + i] = oacc[1][i]; }
        s[8] = mrun; s[9] = lrun;
    }
    __syncthreads();
    if (halfid == 0) {
        const float* s = &mb[wl][lane][0];
        float m1 = s[8], l1 = s[9];
        float mF = fmaxf(mrun, m1);
        float f0 = exp2f(mrun - mF);
        float f1 = exp2f(m1 - mF);
        float invl = 1.0f / (lrun * f0 + l1 * f1);
        #pragma unroll
        for (int mt = 0; mt < 2; mt++) {
            f32x4 ov;
            #pragma unroll
            for (int i = 0; i < 4; i++)
                ov[i] = (oacc[mt][i] * f0 + s[mt * 4 + i] * f1) * invl;
            *(f32x4*)(ob + ((size_t)(b * L_ + qrow) << 8) + h * 32 + mt * 16 + (lg << 2)) = ov;
        }
    }
}

// ---------------------------------------------------------------------------
extern "C" void kernel_launch(void* const* d_in, const int* in_sizes, int n_in,
                              void* d_out, int out_size, void* d_ws, size_t ws_size,
                              hipStream_t stream)
{
    const float* feat = (const float*)d_in[0];
    const float* src  = (const float*)d_in[1];
    const float* Wq   = (const float*)d_in[2];
    const float* bq   = (const float*)d_in[3];
    const float* Wk   = (const float*)d_in[4];
    const float* bk   = (const float*)d_in[5];
    const float* Wv   = (const float*)d_in[6];
    const float* bv   = (const float*)d_in[7];
    const float* Wo   = (const float*)d_in[8];
    const float* bo   = (const float*)d_in[9];
    float* out = (float*)d_out;

    float* ws = (float*)d_ws;
    const size_t NE = (size_t)M_ * C_;        // 2M elements
    // layout: kv fp32 (8MB) | ob fp32 (8MB) | qbf (4MB) | kbf (4MB) | vbf (4MB)
    float* kv = ws;
    float* ob = ws + NE;
    unsigned short* qbf = (unsigned short*)(ws + 2 * NE);
    unsigned short* kbf = qbf + NE;
    unsigned short* vbf = kbf + NE;

    build_kv_kernel<<<(B_ * L_ * C_) / 256, 256, 0, stream>>>(feat, kv);

    // Q carries 1/sqrt(HD) * log2(e) so attention scores are log2-scaled
    const float qscale = 0.17677669529663687f * 1.4426950408889634f;

    dim3 ggrid(M_ / 64, C_ / 64);   // 128 x 4
    gemm_kernel<true,  1><<<ggrid, 256, 0, stream>>>(src, Wq, bq, qbf, nullptr, qscale);
    gemm_kernel<false, 1><<<ggrid, 256, 0, stream>>>(kv,  Wk, bk, kbf, nullptr, 1.0f);
    gemm_kernel<false, 2><<<ggrid, 256, 0, stream>>>(kv,  Wv, bv, vbf, nullptr, 1.0f);

    attn_mfma_kernel<<<1024, 512, 0, stream>>>(qbf, kbf, vbf, ob);

    gemm_kernel<false, 3><<<ggrid, 256, 0, stream>>>(ob, Wo, bo, out, src, 1.0f);
}

// Round 11
// 274.075 us; speedup vs baseline: 1.1701x; 1.1701x over previous
//
#include <hip/hip_runtime.h>
#include <math.h>

#define B_  2
#define C_  256
#define L_  4096           // 64*64 (both Lq and Lkv)
#define M_  (B_*L_)        // 8192

typedef __attribute__((ext_vector_type(8))) short bf16x8;
typedef __attribute__((ext_vector_type(4))) float f32x4;

// fp32 -> bf16 round-to-nearest-even (bit trick; values are tame, no NaN)
__device__ __forceinline__ unsigned short f2bf(float x) {
    unsigned u = __float_as_uint(x);
    unsigned r = u + 0x7fffu + ((u >> 16) & 1u);
    return (unsigned short)(r >> 16);
}

#define GLOAD_LDS16(gp, lp) \
    __builtin_amdgcn_global_load_lds( \
        (const __attribute__((address_space(1))) void*)(gp), \
        (__attribute__((address_space(3))) void*)(lp), 16, 0, 0)

// ---------------------------------------------------------------------------
// kv bf16 [m][256]: j = c*9 + kh*3 + kw ; h=2*oh+kh-1, w=2*ow+kw-1
// ---------------------------------------------------------------------------
__global__ __launch_bounds__(256) void build_kv_kernel(
    const float* __restrict__ feat, unsigned short* __restrict__ kvbf)
{
    int idx = blockIdx.x * 256 + threadIdx.x;   // B*L*C = 4M threads
    int j = idx & (C_ - 1);
    int l = (idx >> 8) & (L_ - 1);
    int b = idx >> 20;
    int c  = j / 9;
    int r  = j - c * 9;
    int kh = r / 3;
    int kw = r - kh * 3;
    int oh = l >> 6, ow = l & 63;
    int h = 2 * oh + kh - 1;
    int w = 2 * ow + kw - 1;
    float val = 0.0f;
    if ((unsigned)h < 128u && (unsigned)w < 128u)
        val = feat[((size_t)(b * C_ + c) * 128 + h) * 128 + w];
    kvbf[idx] = f2bf(val);
}

// ---------------------------------------------------------------------------
// srcT bf16 [b*L + l][c] = src[b][c][l]   (LDS 64x64 tile transpose)
// ---------------------------------------------------------------------------
__global__ __launch_bounds__(256) void transpose_cast_kernel(
    const float* __restrict__ src, unsigned short* __restrict__ srcT)
{
    __shared__ float T[64][68];
    const int id = blockIdx.x;            // 512 = 2 * 4 * 64
    const int b  = id >> 8;
    const int rem = id & 255;
    const int c0 = (rem >> 6) << 6;
    const int l0 = (rem & 63) << 6;
    const int t = threadIdx.x;
    const int tc = t >> 2, tl = (t & 3) * 16;
    const float* srow = src + ((size_t)(b * C_ + c0 + tc) << 12) + l0 + tl;
    #pragma unroll
    for (int i = 0; i < 4; i++)
        *(float4*)&T[tc][tl + i * 4] = *(const float4*)(srow + i * 4);
    __syncthreads();
    const int tl2 = t >> 2, tcc = (t & 3) * 16;
    unsigned short* orow = srcT + ((size_t)(b * L_ + l0 + tl2) << 8) + c0 + tcc;
    union { bf16x8 v; unsigned short s[8]; } p0, p1;
    #pragma unroll
    for (int j = 0; j < 8; j++) p0.s[j] = f2bf(T[tcc + j][tl2]);
    #pragma unroll
    for (int j = 0; j < 8; j++) p1.s[j] = f2bf(T[tcc + 8 + j][tl2]);
    *(bf16x8*)orow = p0.v;
    *(bf16x8*)(orow + 8) = p1.v;
}

// ---------------------------------------------------------------------------
// cast Wq|Wk|Wv (256x256 fp32 each) -> contiguous bf16 [3][65536]
// ---------------------------------------------------------------------------
__global__ __launch_bounds__(256) void cast_w_kernel(
    const float* __restrict__ Wq, const float* __restrict__ Wk,
    const float* __restrict__ Wv, unsigned short* __restrict__ wb)
{
    int t = blockIdx.x * 256 + threadIdx.x;   // 49152 threads, 4 elems each
    int mi = t >> 14;
    int e4 = (t & 16383) * 4;
    const float* W = (mi == 0) ? Wq : (mi == 1) ? Wk : Wv;
    float4 v = *(const float4*)(W + e4);
    ushort4 pk = make_ushort4(f2bf(v.x), f2bf(v.y), f2bf(v.z), f2bf(v.w));
    *(ushort4*)(wb + mi * 65536 + e4) = pk;
}

// ---------------------------------------------------------------------------
// bf16 MFMA projection GEMM: out = A(bf16 [m][256]) x Wb^T(bf16 [n][256]) + bias
// 64x64 tile, K=256 resident in LDS, global_load_lds with inverse-swizzled
// source + swizzled ds_read (XOR (row&7)<<4 -> 2-way banks = free).
// VOUT=0: out bf16 [m][256] = (acc+bias[n])*oscale   (Q folds scale*log2e)
// VOUT=1: out bf16 [b*256+n][4096] (V^T), operands swapped so stores coalesce.
// ---------------------------------------------------------------------------
template <int VOUT>
__global__ __launch_bounds__(256) void proj_gemm_kernel(
    const unsigned short* __restrict__ A, const unsigned short* __restrict__ Wb,
    const float* __restrict__ bias, unsigned short* __restrict__ out, float oscale)
{
    __shared__ __align__(16) char Ash[32768];
    __shared__ __align__(16) char Wsh[32768];
    const int m0 = blockIdx.x * 64;
    const int n0 = blockIdx.y * 64;
    const int t = threadIdx.x;

    #pragma unroll
    for (int i = 0; i < 8; i++) {
        int off = t * 16 + i * 4096;
        int rl = off >> 9;
        int sw = (off & 511) ^ ((rl & 7) << 4);
        GLOAD_LDS16((const char*)A  + (((size_t)(m0 + rl)) << 9) + sw, Ash + off);
        GLOAD_LDS16((const char*)Wb + (((size_t)(n0 + rl)) << 9) + sw, Wsh + off);
    }
    __syncthreads();

    const int lane = t & 63, w = t >> 6;
    const int lg = lane >> 4, lc = lane & 15;
    const int wm = w & 1, wn = w >> 1;

    f32x4 acc[2][2];
    #pragma unroll
    for (int i = 0; i < 2; i++)
        #pragma unroll
        for (int j = 0; j < 2; j++)
            acc[i][j] = (f32x4){0.f, 0.f, 0.f, 0.f};

    #pragma unroll
    for (int ks = 0; ks < 8; ks++) {
        bf16x8 af[2], wf[2];
        #pragma unroll
        for (int g = 0; g < 2; g++) {
            int ra = wm * 32 + g * 16 + lc;
            af[g] = *(const bf16x8*)(Ash + ra * 512 + ((ks * 64 + lg * 16) ^ ((ra & 7) << 4)));
            int rw = wn * 32 + g * 16 + lc;
            wf[g] = *(const bf16x8*)(Wsh + rw * 512 + ((ks * 64 + lg * 16) ^ ((rw & 7) << 4)));
        }
        #pragma unroll
        for (int mg = 0; mg < 2; mg++)
            #pragma unroll
            for (int ng = 0; ng < 2; ng++)
                acc[mg][ng] = VOUT
                    ? __builtin_amdgcn_mfma_f32_16x16x32_bf16(wf[ng], af[mg], acc[mg][ng], 0, 0, 0)
                    : __builtin_amdgcn_mfma_f32_16x16x32_bf16(af[mg], wf[ng], acc[mg][ng], 0, 0, 0);
    }

    if (VOUT == 0) {
        // D row = m (A rows), col = n (W rows)
        #pragma unroll
        for (int mg = 0; mg < 2; mg++) {
            int m = m0 + wm * 32 + mg * 16 + lg * 4;
            #pragma unroll
            for (int ng = 0; ng < 2; ng++) {
                int n = n0 + wn * 32 + ng * 16 + lc;
                float bb = bias[n];
                #pragma unroll
                for (int i = 0; i < 4; i++)
                    out[(size_t)(m + i) * 256 + n] = f2bf((acc[mg][ng][i] + bb) * oscale);
            }
        }
    } else {
        // D row = n (W rows), col = m (A rows); V^T[b*256+n][key=m]
        int b = m0 >> 12, key = m0 & (L_ - 1);
        #pragma unroll
        for (int ng = 0; ng < 2; ng++)
            #pragma unroll
            for (int i = 0; i < 4; i++) {
                int n = n0 + wn * 32 + ng * 16 + lg * 4 + i;
                float bb = bias[n];
                #pragma unroll
                for (int mg = 0; mg < 2; mg++) {
                    int m = key + wm * 32 + mg * 16 + lc;
                    out[((size_t)(b * 256 + n) << 12) + m] = f2bf(acc[mg][ng][i] + bb);
                }
            }
    }
}

// ---------------------------------------------------------------------------
// O-projection, fp32 VALU (accuracy hedge: feeds the src gate directly).
// out[b*C*L + n*L + l] = (sum_c A[m][c]*W[n][c] + bias[n]) * src[same]
// ---------------------------------------------------------------------------
__global__ __launch_bounds__(256) void o_proj_kernel(
    const float* __restrict__ A, const float* __restrict__ W,
    const float* __restrict__ bias, float* __restrict__ out,
    const float* __restrict__ src)
{
    __shared__ float As[32][68];
    __shared__ float Ws[32][68];

    const int m0 = blockIdx.x * 64;
    const int n0 = blockIdx.y * 64;
    const int t  = threadIdx.x;
    const int tm = t >> 4;
    const int tn = t & 15;

    float acc[4][4] = {};

    for (int k0 = 0; k0 < C_; k0 += 32) {
        #pragma unroll
        for (int u = t; u < 512; u += 256) {
            int row = u >> 3, c4 = u & 7;
            float4 val = *(const float4*)(A + (size_t)(m0 + row) * C_ + k0 + c4 * 4);
            As[c4 * 4 + 0][row] = val.x;
            As[c4 * 4 + 1][row] = val.y;
            As[c4 * 4 + 2][row] = val.z;
            As[c4 * 4 + 3][row] = val.w;
        }
        #pragma unroll
        for (int u = t; u < 512; u += 256) {
            int row = u >> 3, c4 = u & 7;
            float4 val = *(const float4*)(W + (size_t)(n0 + row) * C_ + k0 + c4 * 4);
            Ws[c4 * 4 + 0][row] = val.x;
            Ws[c4 * 4 + 1][row] = val.y;
            Ws[c4 * 4 + 2][row] = val.z;
            Ws[c4 * 4 + 3][row] = val.w;
        }
        __syncthreads();
        #pragma unroll
        for (int kk = 0; kk < 32; kk++) {
            float4 a4 = *(float4*)&As[kk][tm * 4];
            float4 w4 = *(float4*)&Ws[kk][tn * 4];
            float a[4] = {a4.x, a4.y, a4.z, a4.w};
            float wv[4] = {w4.x, w4.y, w4.z, w4.w};
            #pragma unroll
            for (int i = 0; i < 4; i++)
                #pragma unroll
                for (int jj = 0; jj < 4; jj++)
                    acc[i][jj] += a[i] * wv[jj];
        }
        __syncthreads();
    }

    #pragma unroll
    for (int i = 0; i < 4; i++) {
        int m = m0 + tm * 4 + i;
        int b = m >> 12, l = m & (L_ - 1);
        #pragma unroll
        for (int jj = 0; jj < 4; jj++) {
            int n = n0 + tn * 4 + jj;
            float val = acc[i][jj] + bias[n];
            size_t oidx = (size_t)(b * C_ + n) * L_ + l;
            out[oidx] = val * src[oidx];
        }
    }
}

// ---------------------------------------------------------------------------
// MFMA flash attention, K-split x2 (UNCHANGED from round 8 — isolates the
// projection-GEMM delta). See round-8 notes for layout derivations.
// ---------------------------------------------------------------------------
__global__ __launch_bounds__(512) void attn_mfma_kernel(
    const unsigned short* __restrict__ qbf,   // [M][256] bf16 (Q pre-scaled)
    const unsigned short* __restrict__ kbf,   // [M][256] bf16 row-major
    const unsigned short* __restrict__ vbf,   // [B*256][4096] bf16 (V^T)
    float* __restrict__ ob)                   // [M][256] fp32 row-major
{
    __shared__ __align__(16) char Ksh[2][4096];
    __shared__ __align__(16) char Vsh[2][4096];
    __shared__ float mb[4][64][11];

    const int id   = blockIdx.x;
    const int xcd  = id & 7;
    const int slot = id >> 3;
    const int bh   = xcd + 8 * (slot >> 6);
    const int qt   = slot & 63;
    const int b = bh >> 3, h = bh & 7;

    const int t      = threadIdx.x;
    const int lane   = t & 63;
    const int wl     = (t >> 6) & 3;
    const int halfid = t >> 8;
    const int th     = t & 255;
    const int lg     = lane >> 4;
    const int lc     = lane & 15;

    const int qrow = qt * 64 + wl * 16 + lc;
    const bf16x8 qf = *(const bf16x8*)(qbf + ((size_t)(b * L_ + qrow) << 8) + h * 32 + (lg << 3));

    const char* kg = (const char*)kbf
        + ((size_t)(b * L_ + halfid * 2048 + wl * 16 + lc) << 9) + h * 64 + (lg << 4);
    const int vmt = (t >> 7) & 1, vks = wl & 1;
    const char* vg = (const char*)vbf
        + ((size_t)(b * 256 + h * 32 + vmt * 16 + lc) << 13)
        + ((size_t)(halfid * 2048 + vks * 32 + (lg << 3)) << 1);
    char* kdst = Ksh[halfid] + th * 16;
    char* vdst = Vsh[halfid] + th * 16;
    const char* kbase = Ksh[halfid];
    const char* vbase = Vsh[halfid];

    f32x4 oacc[2];
    oacc[0] = (f32x4){0.f, 0.f, 0.f, 0.f};
    oacc[1] = (f32x4){0.f, 0.f, 0.f, 0.f};
    float mrun = -INFINITY, lrun = 0.0f;
    const f32x4 zero4 = (f32x4){0.f, 0.f, 0.f, 0.f};

    for (int kt = 0; kt < 32; kt++) {
        __syncthreads();
        GLOAD_LDS16(kg + (size_t)kt * 32768, kdst);
        GLOAD_LDS16(vg + (size_t)kt * 128,   vdst);
        __syncthreads();

        f32x4 sa[4];
        #pragma unroll
        for (int f = 0; f < 4; f++) {
            bf16x8 kf = *(const bf16x8*)(kbase + f * 1024 + lane * 16);
            sa[f] = __builtin_amdgcn_mfma_f32_16x16x32_bf16(kf, qf, zero4, 0, 0, 0);
        }

        float sv[16];
        #pragma unroll
        for (int f = 0; f < 4; f++)
            #pragma unroll
            for (int i = 0; i < 4; i++)
                sv[f * 4 + i] = sa[f][i];
        float t0 = fmaxf(fmaxf(sv[0], sv[1]),  fmaxf(sv[2], sv[3]));
        float t1 = fmaxf(fmaxf(sv[4], sv[5]),  fmaxf(sv[6], sv[7]));
        float t2 = fmaxf(fmaxf(sv[8], sv[9]),  fmaxf(sv[10], sv[11]));
        float t3 = fmaxf(fmaxf(sv[12], sv[13]), fmaxf(sv[14], sv[15]));
        float tmax = fmaxf(fmaxf(t0, t1), fmaxf(t2, t3));
        tmax = fmaxf(tmax, __shfl_xor(tmax, 16));
        tmax = fmaxf(tmax, __shfl_xor(tmax, 32));
        float mnew   = fmaxf(mrun, tmax);
        float factor = exp2f(mrun - mnew);
        float pv[16];
        float ps = 0.f;
        #pragma unroll
        for (int j2 = 0; j2 < 16; j2++) {
            float p = exp2f(sv[j2] - mnew);
            pv[j2] = p;
            ps += p;
        }
        ps += __shfl_xor(ps, 16);
        ps += __shfl_xor(ps, 32);
        lrun = lrun * factor + ps;
        mrun = mnew;
        #pragma unroll
        for (int i = 0; i < 4; i++) { oacc[0][i] *= factor; oacc[1][i] *= factor; }

        unsigned W8[8];
        #pragma unroll
        for (int f = 0; f < 4; f++)
            #pragma unroll
            for (int m2 = 0; m2 < 2; m2++)
                W8[f * 2 + m2] = (unsigned)f2bf(pv[f * 4 + 2 * m2])
                               | ((unsigned)f2bf(pv[f * 4 + 2 * m2 + 1]) << 16);

        #pragma unroll
        for (int ks = 0; ks < 2; ks++) {
            union { unsigned u[4]; bf16x8 v; } bu;
            #pragma unroll
            for (int j = 0; j < 4; j++) {
                int srcl = lc + 16 * ((lg & 1) * 2 + (j >> 1));
                unsigned va = (unsigned)__shfl((int)W8[(ks * 2) * 2 + (j & 1)], srcl);
                unsigned vb = (unsigned)__shfl((int)W8[(ks * 2 + 1) * 2 + (j & 1)], srcl);
                bu.u[j] = (lg >= 2) ? vb : va;
            }
            bf16x8 v0 = *(const bf16x8*)(vbase + 0 * 2048 + ks * 1024 + lane * 16);
            bf16x8 v1 = *(const bf16x8*)(vbase + 1 * 2048 + ks * 1024 + lane * 16);
            oacc[0] = __builtin_amdgcn_mfma_f32_16x16x32_bf16(v0, bu.v, oacc[0], 0, 0, 0);
            oacc[1] = __builtin_amdgcn_mfma_f32_16x16x32_bf16(v1, bu.v, oacc[1], 0, 0, 0);
        }
    }

    __syncthreads();
    if (halfid == 1) {
        float* s = &mb[wl][lane][0];
        #pragma unroll
        for (int i = 0; i < 4; i++) { s[i] = oacc[0][i]; s[4 + i] = oacc[1][i]; }
        s[8] = mrun; s[9] = lrun;
    }
    __syncthreads();
    if (halfid == 0) {
        const float* s = &mb[wl][lane][0];
        float m1 = s[8], l1 = s[9];
        float mF = fmaxf(mrun, m1);
        float f0 = exp2f(mrun - mF);
        float f1 = exp2f(m1 - mF);
        float invl = 1.0f / (lrun * f0 + l1 * f1);
        #pragma unroll
        for (int mt = 0; mt < 2; mt++) {
            f32x4 ov;
            #pragma unroll
            for (int i = 0; i < 4; i++)
                ov[i] = (oacc[mt][i] * f0 + s[mt * 4 + i] * f1) * invl;
            *(f32x4*)(ob + ((size_t)(b * L_ + qrow) << 8) + h * 32 + mt * 16 + (lg << 2)) = ov;
        }
    }
}

// ---------------------------------------------------------------------------
extern "C" void kernel_launch(void* const* d_in, const int* in_sizes, int n_in,
                              void* d_out, int out_size, void* d_ws, size_t ws_size,
                              hipStream_t stream)
{
    const float* feat = (const float*)d_in[0];
    const float* src  = (const float*)d_in[1];
    const float* Wq   = (const float*)d_in[2];
    const float* bq   = (const float*)d_in[3];
    const float* Wk   = (const float*)d_in[4];
    const float* bk   = (const float*)d_in[5];
    const float* Wv   = (const float*)d_in[6];
    const float* bv   = (const float*)d_in[7];
    const float* Wo   = (const float*)d_in[8];
    const float* bo   = (const float*)d_in[9];
    float* out = (float*)d_out;

    float* ws = (float*)d_ws;
    const size_t NE = (size_t)M_ * C_;        // 2M elements
    // ob f32 (8MB) | qbf kbf vbf kvbf srcT bf16 (5x4MB) | wb bf16 (384KB)
    float* ob = ws;
    unsigned short* qbf  = (unsigned short*)(ws + NE);
    unsigned short* kbf  = qbf + NE;
    unsigned short* vbf  = kbf + NE;
    unsigned short* kvbf = vbf + NE;
    unsigned short* srcT = kvbf + NE;
    unsigned short* wb   = srcT + NE;

    // Q carries 1/sqrt(HD) * log2(e) so attention scores are log2-scaled
    const float qscale = 0.17677669529663687f * 1.4426950408889634f;

    build_kv_kernel<<<(B_ * L_ * C_) / 256, 256, 0, stream>>>(feat, kvbf);
    transpose_cast_kernel<<<512, 256, 0, stream>>>(src, srcT);
    cast_w_kernel<<<192, 256, 0, stream>>>(Wq, Wk, Wv, wb);

    dim3 pgrid(M_ / 64, C_ / 64);   // 128 x 4
    proj_gemm_kernel<0><<<pgrid, 256, 0, stream>>>(srcT, wb,          bq, qbf, qscale);
    proj_gemm_kernel<0><<<pgrid, 256, 0, stream>>>(kvbf, wb + 65536,  bk, kbf, 1.0f);
    proj_gemm_kernel<1><<<pgrid, 256, 0, stream>>>(kvbf, wb + 131072, bv, vbf, 1.0f);

    attn_mfma_kernel<<<1024, 512, 0, stream>>>(qbf, kbf, vbf, ob);

    o_proj_kernel<<<pgrid, 256, 0, stream>>>(ob, Wo, bo, out, src);
}